// Round 7
// baseline (102.135 us; speedup 1.0000x reference)
//
#include <hip/hip_runtime.h>
#include <stdint.h>

typedef unsigned long long u64;
typedef unsigned int u32;

#define NBOX 8192
#define ACMAX 1024          // bound on #active boxes (expected ~820)
#define NCH 16              // ACMAX/64 chunks
#define CONF 0.25f
#define IOU_T 0.45f

// ---- workspace layout (bytes). Poison-safe: 0xAA floats read as -3e-13
// (< CONF => invalid) so no zero-init pass is needed anywhere. ----
#define OFF_DONE   0                           // u32 ticket counter
#define OFF_CX1    256                         // compacted, ACMAX floats each
#define OFF_CY1    (OFF_CX1 + ACMAX * 4)
#define OFF_CX2    (OFF_CX1 + 2 * ACMAX * 4)
#define OFF_CY2    (OFF_CX1 + 3 * ACMAX * 4)
#define OFF_CSC    (OFF_CX1 + 4 * ACMAX * 4)
#define OFF_CAR    (OFF_CX1 + 5 * ACMAX * 4)
#define OFF_ROFC   (OFF_CX1 + 6 * ACMAX * 4)   // int per compacted slot
#define OFF_CMASKT (OFF_CX1 + 7 * ACMAX * 4)   // NCH * ACMAX * 8 = 128 KB

// strictly monotone float -> u32 (sign-magnitude to biased)
__device__ inline u32 encf(float f) {
    u32 u = __float_as_uint(f);
    return (u & 0x80000000u) ? ~u : (u | 0x80000000u);
}

// ---------------- K1: fused enumeration-sort + scatter ----------------
// (round-6 verified kernel, verbatim; + doneCnt reset, as in round 2/3)
// 256 blocks x 1024 thr. Block b owns i in [b*32, b*32+32).
// ALL 8192 keys staged in LDS at once (73.7 KB) with skew f(j) = j + (j>>3)
// so phase-2 reads are bank-conflict-free. Phase 2 is fully unrolled.
// Key: enc(s)<<32 | (8191-j)<<19 | mult, mult = 1 (+65536 if active).
// One u64 compare == (s_j > s_i) || (s_j == s_i && j < i); low bits never
// decide order for j != i; i's own key gets low=0x1FFFF to exclude self.
__global__ void __launch_bounds__(1024) k_sort(
        const float* __restrict__ p,
        float* __restrict__ cx1, float* __restrict__ cy1,
        float* __restrict__ cx2, float* __restrict__ cy2,
        float* __restrict__ csc, float* __restrict__ car,
        int* __restrict__ rofc, float* __restrict__ out,
        u32* __restrict__ doneCnt) {
    #pragma clang fp contract(off)
    int t = threadIdx.x;
    int b = blockIdx.x;
    if (b == 0 && t == 0) *doneCnt = 0u;   // reset ticket (poison-unsafe)
    __shared__ u64 keys[9216];       // slot f(j) = j + (j>>3), skewed
    __shared__ u32 accs[128][36];    // [js][i-col], padded
    __shared__ u32 accs2[8][32];
    __shared__ float redm[16];
    __shared__ float s_gmax;

    int il4 = (t & 7) * 4;           // first of 4 i-columns
    int js  = t >> 3;                // j-slice 0..127 (8 j per w-stripe)
    int ibase = b * 32;

    u64 Ki[4];
    #pragma unroll
    for (int q = 0; q < 4; q++) {
        int i = ibase + il4 + q;
        u32 e = encf(p[4 * NBOX + i]);
        Ki[q] = ((u64)e << 32) | ((u64)(8191 - i) << 19) | 0x1FFFFull;
    }

    // ---- phase 1: decode 8 boxes/thread, build keys, coord-max ----
    float mloc = -3.4e38f;
    #pragma unroll
    for (int w = 0; w < 8; w++) {
        int j = w * 1024 + t;
        float cxj = p[j], cyj = p[NBOX + j];
        float pwj = p[2 * NBOX + j], phj = p[3 * NBOX + j];
        float sj = p[4 * NBOX + j];
        float hx = pwj * 0.5f, hy = phj * 0.5f;
        float x1 = cxj - hx, y1 = cyj - hy, x2 = cxj + hx, y2 = cyj + hy;
        bool act = (sj > CONF) && (x2 > x1) && (y2 > y1);
        mloc = fmaxf(mloc, fmaxf(fmaxf(x1, y1), fmaxf(x2, y2)));
        u32 e = encf(sj);
        u32 mult = act ? 65537u : 1u;
        keys[j + (j >> 3)] =
            ((u64)e << 32) | ((u64)(8191 - j) << 19) | (u64)mult;
    }
    __syncthreads();                 // ONE staging barrier

    // ---- phase 2: 64 skewed LDS reads + 256 compare-accumulates ----
    // index for (w,m): f(w*1024 + js*8 + m) = w*1152 + js*9 + m
    u32 acc[4] = {0u, 0u, 0u, 0u};
    int base = js * 9;
    #pragma unroll
    for (int w = 0; w < 8; w++) {
        #pragma unroll
        for (int m = 0; m < 8; m++) {
            u64 kj = keys[base + w * 1152 + m];
            u32 mm = (u32)kj & 0x1FFFFu;
            acc[0] += (kj > Ki[0]) ? mm : 0u;
            acc[1] += (kj > Ki[1]) ? mm : 0u;
            acc[2] += (kj > Ki[2]) ? mm : 0u;
            acc[3] += (kj > Ki[3]) ? mm : 0u;
        }
    }
    #pragma unroll
    for (int q = 0; q < 4; q++) accs[js][il4 + q] = acc[q];
    #pragma unroll
    for (int o = 32; o > 0; o >>= 1) mloc = fmaxf(mloc, __shfl_xor(mloc, o, 64));
    if ((t & 63) == 0) redm[t >> 6] = mloc;
    __syncthreads();
    if (t < 256) {
        int il = t & 31, part = t >> 5;
        u32 s = 0;
        #pragma unroll
        for (int q = 0; q < 16; q++) s += accs[part * 16 + q][il];
        accs2[part][il] = s;
    }
    if (t == 0) {
        float g = redm[0];
        #pragma unroll
        for (int k = 1; k < 16; k++) g = fmaxf(g, redm[k]);
        s_gmax = g;
    }
    __syncthreads();
    if (t < 32) {
        u32 total = 0;
        #pragma unroll
        for (int part = 0; part < 8; part++) total += accs2[part][t];
        int r = (int)(total & 0xFFFFu);
        int cr = (int)(total >> 16);
        int i = ibase + t;
        float scale = (s_gmax <= 1.0f) ? 416.0f : 1.0f;
        float cx = p[i], cy = p[NBOX + i];
        float pw = p[2 * NBOX + i], ph = p[3 * NBOX + i];
        float s = p[4 * NBOX + i];
        float hx = pw * 0.5f, hy = ph * 0.5f;
        float x1 = cx - hx, y1 = cy - hy, x2 = cx + hx, y2 = cy + hy;
        bool a = (s > CONF) && (x2 > x1) && (y2 > y1);
        float bx1 = x1 * scale, by1 = y1 * scale;
        float bx2 = x2 * scale, by2 = y2 * scale;
        float aw = fmaxf(bx2 - bx1, 0.0f);
        float ah = fmaxf(by2 - by1, 0.0f);
        float area = aw * ah;
        bool ok = a && (cr < ACMAX);
        if (ok) {
            cx1[cr] = bx1; cy1[cr] = by1; cx2[cr] = bx2; cy2[cr] = by2;
            csc[cr] = s; car[cr] = area; rofc[cr] = r;
        } else {
            bool valid = s > CONF;       // non-active valid: always kept
            float* o = out + (size_t)r * 6;
            o[0] = valid ? bx1 / 416.0f : 0.0f;
            o[1] = valid ? by1 / 416.0f : 0.0f;
            o[2] = valid ? bx2 / 416.0f : 0.0f;
            o[3] = valid ? by2 / 416.0f : 0.0f;
            o[4] = valid ? s : 0.0f;
            o[5] = 0.0f;
        }
    }
}

// ------ K2: mask tiles (16 blocks) + NO-SPIN ticket; last block resolves ---
// Block b = row-chunk b (rows staged in LDS once); wave wv = col-chunk wv
// (j == t): the verified k_mask inner loop. After its tiles, each block:
// __syncthreads (drains all waves' stores) -> __threadfence (cache-wide L2
// writeback) -> one atomicAdd(ACQ_REL, agent) ticket. Ticket 15 == last:
// all 15 other releases happen-before its acquire (which invalidates
// L1/L2 cache-wide), so its plain reads of cmaskT are fresh. No thread
// ever waits -> none of round-3's 47us spin pathology can occur.
__global__ void __launch_bounds__(1024) k_maskfinal(
        const float* __restrict__ cx1, const float* __restrict__ cy1,
        const float* __restrict__ cx2, const float* __restrict__ cy2,
        const float* __restrict__ car, const float* __restrict__ csc,
        const int* __restrict__ rofc, u64* __restrict__ cmaskT,
        u32* __restrict__ doneCnt, float* __restrict__ out) {
    #pragma clang fp contract(off)
    int t = threadIdx.x;
    int b = blockIdx.x;
    __shared__ float sx1[64], sy1[64], sx2[64], sy2[64], sa[64];
    __shared__ u32 s_ticket;
    __shared__ u64 keptArr[NCH];

    // ---------------- mask tiles (all 16 blocks) ----------------
    if (t < 64) {
        sx1[t] = cx1[b * 64 + t]; sy1[t] = cy1[b * 64 + t];
        sx2[t] = cx2[b * 64 + t]; sy2[t] = cy2[b * 64 + t];
        sa[t]  = car[b * 64 + t];
    }
    __syncthreads();
    int lane = t & 63;
    int j = t;                       // col == t; wave wv covers a 64-col chunk
    u64 rv = __ballot(csc[b * 64 + lane] > CONF);
    u64 cv = __ballot(csc[j] > CONF);
    if (rv != 0ull && cv != 0ull) {  // wave-uniform branch
        float xj1 = cx1[j], yj1 = cy1[j];
        float xj2 = cx2[j], yj2 = cy2[j], aj = car[j];
        u64 w = 0;
        for (int ii = 0; ii < 64; ii++) {
            float xx1 = fmaxf(sx1[ii], xj1);
            float yy1 = fmaxf(sy1[ii], yj1);
            float xx2 = fminf(sx2[ii], xj2);
            float yy2 = fminf(sy2[ii], yj2);
            float iw = fmaxf(xx2 - xx1, 0.0f);
            float ih = fmaxf(yy2 - yy1, 0.0f);
            float inter = iw * ih;
            float uni = sa[ii] + aj - inter;
            bool sup = (uni > 0.0f) && (inter / uni > IOU_T);
            w |= ((u64)(sup ? 1u : 0u)) << ii;
        }
        cmaskT[(size_t)b * ACMAX + j] = w;
    }
    __syncthreads();                 // every wave's stores drained (vmcnt(0))
    __threadfence();                 // cache-wide L2 writeback, device scope
    if (t == 0) {
        s_ticket = __hip_atomic_fetch_add(doneCnt, 1u, __ATOMIC_ACQ_REL,
                                          __HIP_MEMORY_SCOPE_AGENT);
    }
    __syncthreads();
    if (s_ticket != 15u) return;     // not last: done

    // ---------------- resolve + emit (last block only) ----------------
    // (verified round-6 k_final body, verbatim) Greedy-NMS kept-set is the
    // UNIQUE fixpoint of kept = valid & ~sup(kept); iterate from
    // kept0 = valid until stable. Cap guarantees exit.
    int wv = t >> 6;
    float s = csc[t];
    bool valid = s > CONF;
    u64 col[NCH];
    #pragma unroll
    for (int w = 0; w < NCH; w++) col[w] = cmaskT[(size_t)w * ACMAX + t];
    u64 validm = __ballot(valid);
    if ((t & 63) == 0) keptArr[wv] = validm; // optimistic init
    __syncthreads();
    int jj = t & 63;
    u64 below = (jj == 0) ? 0ull : (~0ull >> (64 - jj));  // bits 0..j-1
    for (int iter = 0; iter < 1024; ++iter) {
        bool sup = false;
        for (int w = 0; w < wv; ++w)                     // earlier chunks
            sup |= (col[w] & keptArr[w]) != 0ull;
        sup |= (col[wv] & keptArr[wv] & below) != 0ull;  // own chunk, i<j
        u64 nk = validm & ~__ballot(sup);
        int ch = (nk != keptArr[wv]) ? 1 : 0;            // wave-uniform
        __syncthreads();                                 // readers done
        if (jj == 0) keptArr[wv] = nk;
        if (!__syncthreads_or(ch)) break;                // publish + test
    }
    if (valid) {
        bool kb = (keptArr[wv] >> jj) & 1ull;
        int r = rofc[t];
        float* o = out + (size_t)r * 6;
        o[0] = kb ? cx1[t] / 416.0f : 0.0f;
        o[1] = kb ? cy1[t] / 416.0f : 0.0f;
        o[2] = kb ? cx2[t] / 416.0f : 0.0f;
        o[3] = kb ? cy2[t] / 416.0f : 0.0f;
        o[4] = kb ? s : 0.0f;
        o[5] = 0.0f;
    }
}

extern "C" void kernel_launch(void* const* d_in, const int* in_sizes, int n_in,
                              void* d_out, int out_size, void* d_ws, size_t ws_size,
                              hipStream_t stream) {
    const float* preds = (const float*)d_in[0];
    float* out = (float*)d_out;
    char* ws = (char*)d_ws;
    u32* doneCnt = (u32*)(ws + OFF_DONE);
    float* cx1 = (float*)(ws + OFF_CX1);
    float* cy1 = (float*)(ws + OFF_CY1);
    float* cx2 = (float*)(ws + OFF_CX2);
    float* cy2 = (float*)(ws + OFF_CY2);
    float* csc = (float*)(ws + OFF_CSC);
    float* car = (float*)(ws + OFF_CAR);
    int* rofc  = (int*)(ws + OFF_ROFC);
    u64* cmaskT = (u64*)(ws + OFF_CMASKT);

    hipLaunchKernelGGL(k_sort, dim3(256), dim3(1024), 0, stream,
                       preds, cx1, cy1, cx2, cy2, csc, car, rofc, out, doneCnt);
    hipLaunchKernelGGL(k_maskfinal, dim3(16), dim3(1024), 0, stream,
                       cx1, cy1, cx2, cy2, car, csc, rofc, cmaskT, doneCnt, out);
}

// Round 8
// 91.685 us; speedup vs baseline: 1.1140x; 1.1140x over previous
//
#include <hip/hip_runtime.h>
#include <stdint.h>

typedef unsigned long long u64;
typedef unsigned int u32;

#define NBOX 8192
#define ACMAX 1024          // bound on #active boxes (expected ~820)
#define NCH 16              // ACMAX/64 chunks
#define CONF 0.25f
#define IOU_T 0.45f

// ---- workspace layout (bytes). Poison-safe: 0xAA floats read as -3e-13
// (< CONF => invalid) so no zero-init pass is needed anywhere. ----
#define OFF_CX1    256                         // compacted, ACMAX floats each
#define OFF_CY1    (OFF_CX1 + ACMAX * 4)
#define OFF_CX2    (OFF_CX1 + 2 * ACMAX * 4)
#define OFF_CY2    (OFF_CX1 + 3 * ACMAX * 4)
#define OFF_CSC    (OFF_CX1 + 4 * ACMAX * 4)
#define OFF_CAR    (OFF_CX1 + 5 * ACMAX * 4)
#define OFF_ROFC   (OFF_CX1 + 6 * ACMAX * 4)   // int per compacted slot
#define OFF_CMASKT (OFF_CX1 + 7 * ACMAX * 4)   // NCH * ACMAX * 8 = 128 KB

// strictly monotone float -> u32 (sign-magnitude to biased)
__device__ inline u32 encf(float f) {
    u32 u = __float_as_uint(f);
    return (u & 0x80000000u) ? ~u : (u | 0x80000000u);
}

// ---------------- K1: fused enumeration-sort + scatter ----------------
// 256 blocks x 1024 thr. Block b owns i in [b*32, b*32+32).
// ALL 8192 keys staged in LDS at once (73.7 KB) with skew f(j) = j + (j>>3)
// so phase-2 reads are bank-conflict-free (byte stride 72 -> bank stride 18,
// coprime with 32). Phase 2 is fully unrolled, compile-time ds offsets.
// v3: phase 1 uses float4 plane loads (40 -> 10 global load insts/thread);
// j = w*4096 + 4t + m. Skew group is constant across the 4-vector:
// 4t mod 8 in {0,4} => (4t+m)>>3 == t>>1 for m<4, so
// f(4t+m) = 4t + (t>>1) + m -- 4 consecutive LDS slots.
// Key: enc(s)<<32 | (8191-j)<<19 | mult, mult = 1 (+65536 if active).
// One u64 compare == (s_j > s_i) || (s_j == s_i && j < i); low bits never
// decide order for j != i; i's own key gets low=0x1FFFF to exclude self.
__global__ void __launch_bounds__(1024) k_sort(
        const float* __restrict__ p,
        float* __restrict__ cx1, float* __restrict__ cy1,
        float* __restrict__ cx2, float* __restrict__ cy2,
        float* __restrict__ csc, float* __restrict__ car,
        int* __restrict__ rofc, float* __restrict__ out) {
    #pragma clang fp contract(off)
    int t = threadIdx.x;
    int b = blockIdx.x;
    __shared__ u64 keys[9216];       // slot f(j) = j + (j>>3), skewed
    __shared__ u32 accs[128][36];    // [js][i-col], padded
    __shared__ u32 accs2[8][32];
    __shared__ float redm[16];
    __shared__ float s_gmax;

    int il4 = (t & 7) * 4;           // first of 4 i-columns
    int js  = t >> 3;                // j-slice 0..127 (8 j per w-stripe)
    int ibase = b * 32;

    u64 Ki[4];
    #pragma unroll
    for (int q = 0; q < 4; q++) {
        int i = ibase + il4 + q;
        u32 e = encf(p[4 * NBOX + i]);
        Ki[q] = ((u64)e << 32) | ((u64)(8191 - i) << 19) | 0x1FFFFull;
    }

    // ---- phase 1: decode 8 boxes/thread (float4 loads), build keys ----
    float mloc = -3.4e38f;
    auto mk = [&](float cxj, float cyj, float pwj, float phj, float sj,
                  int jj, int slot) {
        float hx = pwj * 0.5f, hy = phj * 0.5f;
        float x1 = cxj - hx, y1 = cyj - hy, x2 = cxj + hx, y2 = cyj + hy;
        bool act = (sj > CONF) && (x2 > x1) && (y2 > y1);
        mloc = fmaxf(mloc, fmaxf(fmaxf(x1, y1), fmaxf(x2, y2)));
        u32 e = encf(sj);
        u32 mult = act ? 65537u : 1u;
        keys[slot] = ((u64)e << 32) | ((u64)(8191 - jj) << 19) | (u64)mult;
    };
    #pragma unroll
    for (int w = 0; w < 2; w++) {
        int j0 = w * 4096 + t * 4;
        float4 cxv = *reinterpret_cast<const float4*>(&p[j0]);
        float4 cyv = *reinterpret_cast<const float4*>(&p[NBOX + j0]);
        float4 pwv = *reinterpret_cast<const float4*>(&p[2 * NBOX + j0]);
        float4 phv = *reinterpret_cast<const float4*>(&p[3 * NBOX + j0]);
        float4 sv  = *reinterpret_cast<const float4*>(&p[4 * NBOX + j0]);
        int fbase = j0 + (j0 >> 3);   // f(j0); group const across m=0..3
        mk(cxv.x, cyv.x, pwv.x, phv.x, sv.x, j0 + 0, fbase + 0);
        mk(cxv.y, cyv.y, pwv.y, phv.y, sv.y, j0 + 1, fbase + 1);
        mk(cxv.z, cyv.z, pwv.z, phv.z, sv.z, j0 + 2, fbase + 2);
        mk(cxv.w, cyv.w, pwv.w, phv.w, sv.w, j0 + 3, fbase + 3);
    }
    __syncthreads();                 // ONE staging barrier

    // ---- phase 2: 64 skewed LDS reads + 256 compare-accumulates ----
    // index for (w,m): f(w*1024 + js*8 + m) = w*1152 + js*9 + m
    u32 acc[4] = {0u, 0u, 0u, 0u};
    int base = js * 9;
    #pragma unroll
    for (int w = 0; w < 8; w++) {
        #pragma unroll
        for (int m = 0; m < 8; m++) {
            u64 kj = keys[base + w * 1152 + m];
            u32 mm = (u32)kj & 0x1FFFFu;
            acc[0] += (kj > Ki[0]) ? mm : 0u;
            acc[1] += (kj > Ki[1]) ? mm : 0u;
            acc[2] += (kj > Ki[2]) ? mm : 0u;
            acc[3] += (kj > Ki[3]) ? mm : 0u;
        }
    }
    #pragma unroll
    for (int q = 0; q < 4; q++) accs[js][il4 + q] = acc[q];
    #pragma unroll
    for (int o = 32; o > 0; o >>= 1) mloc = fmaxf(mloc, __shfl_xor(mloc, o, 64));
    if ((t & 63) == 0) redm[t >> 6] = mloc;
    __syncthreads();
    if (t < 256) {
        int il = t & 31, part = t >> 5;
        u32 s = 0;
        #pragma unroll
        for (int q = 0; q < 16; q++) s += accs[part * 16 + q][il];
        accs2[part][il] = s;
    }
    if (t == 0) {
        float g = redm[0];
        #pragma unroll
        for (int k = 1; k < 16; k++) g = fmaxf(g, redm[k]);
        s_gmax = g;
    }
    __syncthreads();
    if (t < 32) {
        u32 total = 0;
        #pragma unroll
        for (int part = 0; part < 8; part++) total += accs2[part][t];
        int r = (int)(total & 0xFFFFu);
        int cr = (int)(total >> 16);
        int i = ibase + t;
        float scale = (s_gmax <= 1.0f) ? 416.0f : 1.0f;
        float cx = p[i], cy = p[NBOX + i];
        float pw = p[2 * NBOX + i], ph = p[3 * NBOX + i];
        float s = p[4 * NBOX + i];
        float hx = pw * 0.5f, hy = ph * 0.5f;
        float x1 = cx - hx, y1 = cy - hy, x2 = cx + hx, y2 = cy + hy;
        bool a = (s > CONF) && (x2 > x1) && (y2 > y1);
        float bx1 = x1 * scale, by1 = y1 * scale;
        float bx2 = x2 * scale, by2 = y2 * scale;
        float aw = fmaxf(bx2 - bx1, 0.0f);
        float ah = fmaxf(by2 - by1, 0.0f);
        float area = aw * ah;
        bool ok = a && (cr < ACMAX);
        if (ok) {
            cx1[cr] = bx1; cy1[cr] = by1; cx2[cr] = bx2; cy2[cr] = by2;
            csc[cr] = s; car[cr] = area; rofc[cr] = r;
        } else {
            bool valid = s > CONF;       // non-active valid: always kept
            float* o = out + (size_t)r * 6;
            o[0] = valid ? bx1 / 416.0f : 0.0f;
            o[1] = valid ? by1 / 416.0f : 0.0f;
            o[2] = valid ? bx2 / 416.0f : 0.0f;
            o[3] = valid ? by2 / 416.0f : 0.0f;
            o[4] = valid ? s : 0.0f;
            o[5] = 0.0f;
        }
    }
}

// ---------------- K2: IoU bitmask tiles, column-major words ---------------
// (verified verbatim)
__global__ void __launch_bounds__(64) k_mask(
        const float* __restrict__ cx1, const float* __restrict__ cy1,
        const float* __restrict__ cx2, const float* __restrict__ cy2,
        const float* __restrict__ car, const float* __restrict__ csc,
        u64* __restrict__ cmaskT) {
    #pragma clang fp contract(off)
    int t = threadIdx.x;
    int i0 = blockIdx.x * 64, j0 = blockIdx.y * 64;
    u64 rv = __ballot(csc[i0 + t] > CONF);
    u64 cv = __ballot(csc[j0 + t] > CONF);
    if (rv == 0ull || cv == 0ull) return;
    __shared__ float sx1[64], sy1[64], sx2[64], sy2[64], sa[64];
    sx1[t] = cx1[i0 + t]; sy1[t] = cy1[i0 + t];
    sx2[t] = cx2[i0 + t]; sy2[t] = cy2[i0 + t];
    sa[t] = car[i0 + t];
    __syncthreads();
    int j = j0 + t;
    float xj1 = cx1[j], yj1 = cy1[j], xj2 = cx2[j], yj2 = cy2[j], aj = car[j];
    u64 w = 0;
    for (int ii = 0; ii < 64; ii++) {
        float xx1 = fmaxf(sx1[ii], xj1);
        float yy1 = fmaxf(sy1[ii], yj1);
        float xx2 = fminf(sx2[ii], xj2);
        float yy2 = fminf(sy2[ii], yj2);
        float iw = fmaxf(xx2 - xx1, 0.0f);
        float ih = fmaxf(yy2 - yy1, 0.0f);
        float inter = iw * ih;
        float uni = sa[ii] + aj - inter;
        bool sup = (uni > 0.0f) && (inter / uni > IOU_T);
        w |= ((u64)(sup ? 1u : 0u)) << ii;
    }
    cmaskT[(size_t)blockIdx.x * ACMAX + j] = w;
}

// ---------------- K3: Jacobi-fixpoint greedy resolve + emit ---------------
// (verified verbatim) Greedy-NMS kept-set is the UNIQUE fixpoint of
// kept = valid & ~sup(kept); iterate from kept0 = valid until stable.
// Chain depth for random boxes ~1-3 => ~3-5 iterations. Cap guarantees exit.
__global__ void __launch_bounds__(1024) k_final(
        const float* __restrict__ csc, const u64* __restrict__ cmaskT,
        const float* __restrict__ cx1, const float* __restrict__ cy1,
        const float* __restrict__ cx2, const float* __restrict__ cy2,
        const int* __restrict__ rofc, float* __restrict__ out) {
    int t = threadIdx.x;
    __shared__ u64 keptArr[NCH];
    int wv = t >> 6;
    int j = t & 63;
    float s = csc[t];
    bool valid = s > CONF;
    u64 col[NCH];
    #pragma unroll
    for (int w = 0; w < NCH; w++) col[w] = cmaskT[(size_t)w * ACMAX + t];
    u64 validm = __ballot(valid);
    if (j == 0) keptArr[wv] = validm;     // optimistic init: all valid kept
    __syncthreads();
    u64 below = (j == 0) ? 0ull : (~0ull >> (64 - j));   // bits 0..j-1
    for (int iter = 0; iter < 1024; ++iter) {
        bool sup = false;
        for (int w = 0; w < wv; ++w)                     // earlier chunks
            sup |= (col[w] & keptArr[w]) != 0ull;
        sup |= (col[wv] & keptArr[wv] & below) != 0ull;  // own chunk, i<j
        u64 nk = validm & ~__ballot(sup);
        int ch = (nk != keptArr[wv]) ? 1 : 0;            // wave-uniform
        __syncthreads();                                 // readers done
        if (j == 0) keptArr[wv] = nk;
        if (!__syncthreads_or(ch)) break;                // publish + test
    }
    if (valid) {
        bool kb = (keptArr[wv] >> j) & 1ull;
        int r = rofc[t];
        float* o = out + (size_t)r * 6;
        o[0] = kb ? cx1[t] / 416.0f : 0.0f;
        o[1] = kb ? cy1[t] / 416.0f : 0.0f;
        o[2] = kb ? cx2[t] / 416.0f : 0.0f;
        o[3] = kb ? cy2[t] / 416.0f : 0.0f;
        o[4] = kb ? s : 0.0f;
        o[5] = 0.0f;
    }
}

extern "C" void kernel_launch(void* const* d_in, const int* in_sizes, int n_in,
                              void* d_out, int out_size, void* d_ws, size_t ws_size,
                              hipStream_t stream) {
    const float* preds = (const float*)d_in[0];
    float* out = (float*)d_out;
    char* ws = (char*)d_ws;
    float* cx1 = (float*)(ws + OFF_CX1);
    float* cy1 = (float*)(ws + OFF_CY1);
    float* cx2 = (float*)(ws + OFF_CX2);
    float* cy2 = (float*)(ws + OFF_CY2);
    float* csc = (float*)(ws + OFF_CSC);
    float* car = (float*)(ws + OFF_CAR);
    int* rofc  = (int*)(ws + OFF_ROFC);
    u64* cmaskT = (u64*)(ws + OFF_CMASKT);

    hipLaunchKernelGGL(k_sort, dim3(256), dim3(1024), 0, stream,
                       preds, cx1, cy1, cx2, cy2, csc, car, rofc, out);
    hipLaunchKernelGGL(k_mask, dim3(NCH, NCH), dim3(64), 0, stream,
                       cx1, cy1, cx2, cy2, car, csc, cmaskT);
    hipLaunchKernelGGL(k_final, dim3(1), dim3(1024), 0, stream,
                       csc, cmaskT, cx1, cy1, cx2, cy2, rofc, out);
}